// Round 2
// baseline (575.126 us; speedup 1.0000x reference)
//
#include <hip/hip_runtime.h>

// KanvolutionLayer: out[b,o,hw] = (sum_{p,c} x^(p+1) Wp[p,o,c] + bp[o]) / (1 + |sum_{q,c} x^(q+1) Wq[q,o,c]|)
// One MFMA GEMM: M=100352 (b*hw), K=1280 (p*256+c), N=512 (p/q outs interleaved per 16).
// PRECISION: out = P/(1+|Q|) amplifies Q error by out/(1+|Q|) (~644x worst case) -> single bf16
// fails (measured absmax 42). Use 3-product bf16x2 split (Ah*Wh + Al*Wh + Ah*Wl), per-term
// relative error ~3*2^-18, dropping only Al*Wl (~|aw|*2^-18).

typedef __attribute__((ext_vector_type(8))) short bf16x8;           // MFMA A/B frag (4 VGPRs)
typedef __attribute__((ext_vector_type(8))) unsigned short u16x8;
typedef __attribute__((ext_vector_type(4))) float f32x4;            // MFMA C/D frag

#define CIN    256
#define HW3    3136          // 56*56
#define MTOT   100352        // 32*3136 = 784 * 128
#define KTOT   1280
#define LDA    40            // padded LDS row (bf16): 80B rows -> <=2-way bank aliasing (free, m136)
#define WPLANE (512 * 1280)

__device__ __forceinline__ unsigned short f2bf(float f) {
    union { float f; unsigned int u; } cv; cv.f = f;
    unsigned int u = cv.u;
    return (unsigned short)((u + 0x7FFFu + ((u >> 16) & 1u)) >> 16);  // RNE
}
__device__ __forceinline__ float bf2f(unsigned short h) {
    union { unsigned int u; float f; } cv; cv.u = ((unsigned int)h) << 16;
    return cv.f;
}

// Pack weights into bf16 hi/lo planes [512][1280]; row n -> (o,isq):
//   o = (n>>5)*16 + (n&15), isq = (n>>4)&1  (pairs P/Q frags per 16 cols). k = p*256 + c.
__global__ void pack_w_kernel(const float* __restrict__ Wp,
                              const float* __restrict__ Wq,
                              unsigned short* __restrict__ Whi,
                              unsigned short* __restrict__ Wlo) {
    int idx = blockIdx.x * 256 + threadIdx.x;      // [0, 512*1280)
    int n = idx / KTOT;
    int k = idx - n * KTOT;
    int p = k >> 8, c = k & 255;
    int o = ((n >> 5) << 4) + (n & 15);
    int isq = (n >> 4) & 1;
    float v;
    if (isq) v = (p < 4) ? Wq[((size_t)p * 256 + o) * 256 + c] : 0.0f;
    else     v = Wp[((size_t)p * 256 + o) * 256 + c];
    unsigned short h = f2bf(v);
    Whi[idx] = h;
    Wlo[idx] = f2bf(v - bf2f(h));   // exact residual (Sterbenz), then one rounding
}

__global__ __launch_bounds__(256, 2) void kanv_gemm(
    const float* __restrict__ x,
    const unsigned short* __restrict__ Whi,
    const unsigned short* __restrict__ Wlo,
    const float* __restrict__ bp,
    float* __restrict__ out)
{
    __shared__ unsigned short sAh[128 * LDA];
    __shared__ unsigned short sAl[128 * LDA];
    __shared__ unsigned short sBh[128 * LDA];
    __shared__ unsigned short sBl[128 * LDA];

    const int tid  = threadIdx.x;
    const int lane = tid & 63;
    const int wave = tid >> 6;
    const int wm   = wave >> 1;        // wave m-half
    const int wn   = wave & 1;         // wave n-half
    const int col  = lane & 15;
    const int quad = lane >> 4;

    const int nt = blockIdx.x & 3;     // n-tile (4 x 128 = 512)
    const int mt = blockIdx.x >> 2;    // m-tile (784 x 128)
    const int m0 = mt * 128;

    // A-staging role: thread owns (row sm, 16 channels of half chalf)
    const int sm    = tid & 127;
    const int chalf = tid >> 7;
    const int mg  = m0 + sm;
    const int bb  = mg / HW3;
    const int hwl = mg - bb * HW3;
    const float* xbase = x + ((size_t)bb * CIN) * HW3 + hwl;
    const int aoff = sm * LDA + chalf * 16;

    // B-staging role: thread owns row nB, 16-elem k-seg kk0B
    const int nB   = tid >> 1;
    const int kk0B = (tid & 1) * 16;
    const size_t wbase = (size_t)(nt * 128 + nB) * KTOT + kk0B;
    const int boff = nB * LDA + kk0B;

    f32x4 acc[4][4];
#pragma unroll
    for (int mi = 0; mi < 4; ++mi)
#pragma unroll
        for (int ni = 0; ni < 4; ++ni)
            acc[mi][ni] = (f32x4){0.f, 0.f, 0.f, 0.f};

    float xv[16], pw[16];

    for (int g = 0; g < 8; ++g) {
        // load x once per 32-channel group (coalesced: consecutive lanes along hw)
        const float* xp = xbase + (size_t)(g * 32 + chalf * 16) * HW3;
#pragma unroll
        for (int j = 0; j < 16; ++j) xv[j] = xp[(size_t)j * HW3];
#pragma unroll
        for (int j = 0; j < 16; ++j) pw[j] = xv[j];

#pragma unroll
        for (int p = 0; p < 5; ++p) {
            __syncthreads();   // previous chunk's frag reads done

            // ---- stage A: current power split hi/lo (rounded once from fp32) ----
            u16x8 h0, h1, l0, l1;
#pragma unroll
            for (int j = 0; j < 8; ++j) {
                unsigned short h = f2bf(pw[j]);
                h0[j] = h; l0[j] = f2bf(pw[j] - bf2f(h));
                h = f2bf(pw[j + 8]);
                h1[j] = h; l1[j] = f2bf(pw[j + 8] - bf2f(h));
            }
            *(u16x8*)&sAh[aoff]     = h0;
            *(u16x8*)&sAh[aoff + 8] = h1;
            *(u16x8*)&sAl[aoff]     = l0;
            *(u16x8*)&sAl[aoff + 8] = l1;

            // ---- stage B hi/lo ----
            const size_t wo = wbase + (size_t)(p * 256 + g * 32);
            uint4 wh0 = *(const uint4*)(Whi + wo);
            uint4 wh1 = *(const uint4*)(Whi + wo + 8);
            uint4 wl0 = *(const uint4*)(Wlo + wo);
            uint4 wl1 = *(const uint4*)(Wlo + wo + 8);
            *(uint4*)&sBh[boff]     = wh0;
            *(uint4*)&sBh[boff + 8] = wh1;
            *(uint4*)&sBl[boff]     = wl0;
            *(uint4*)&sBl[boff + 8] = wl1;

            __syncthreads();

            // ---- fragments + 3-product MFMA ----
            bf16x8 ah[4], al[4], bh[4], bl[4];
#pragma unroll
            for (int mi = 0; mi < 4; ++mi) {
                const int r = (wm * 64 + mi * 16 + col) * LDA + quad * 8;
                ah[mi] = *(const bf16x8*)&sAh[r];
                al[mi] = *(const bf16x8*)&sAl[r];
            }
#pragma unroll
            for (int ni = 0; ni < 4; ++ni) {
                const int r = (wn * 64 + ni * 16 + col) * LDA + quad * 8;
                bh[ni] = *(const bf16x8*)&sBh[r];
                bl[ni] = *(const bf16x8*)&sBl[r];
            }
#pragma unroll
            for (int mi = 0; mi < 4; ++mi)
#pragma unroll
                for (int ni = 0; ni < 4; ++ni) {
                    acc[mi][ni] = __builtin_amdgcn_mfma_f32_16x16x32_bf16(ah[mi], bh[ni], acc[mi][ni], 0, 0, 0);
                    acc[mi][ni] = __builtin_amdgcn_mfma_f32_16x16x32_bf16(al[mi], bh[ni], acc[mi][ni], 0, 0, 0);
                    acc[mi][ni] = __builtin_amdgcn_mfma_f32_16x16x32_bf16(ah[mi], bl[ni], acc[mi][ni], 0, 0, 0);
                }

            if (p < 4) {
#pragma unroll
                for (int j = 0; j < 16; ++j) pw[j] *= xv[j];   // next power, fp32 (matches ref)
            }
        }
    }

    // ---- epilogue: pair (sum_p, sum_q) frags, bias, divide, float4 store ----
#pragma unroll
    for (int j = 0; j < 2; ++j) {
        const int o = (nt * 4 + wn * 2 + j) * 16 + col;
        const float bias = bp[o];
#pragma unroll
        for (int mi = 0; mi < 4; ++mi) {
            f32x4 sp = acc[mi][2 * j];
            f32x4 sq = acc[mi][2 * j + 1];
            const int mrow = m0 + wm * 64 + mi * 16 + quad * 4;  // 4 consecutive hw, same image
            const int b2  = mrow / HW3;
            const int hw2 = mrow - b2 * HW3;
            float4 v;
            v.x = (sp[0] + bias) / (1.0f + fabsf(sq[0]));
            v.y = (sp[1] + bias) / (1.0f + fabsf(sq[1]));
            v.z = (sp[2] + bias) / (1.0f + fabsf(sq[2]));
            v.w = (sp[3] + bias) / (1.0f + fabsf(sq[3]));
            *(float4*)&out[((size_t)b2 * 256 + o) * HW3 + hw2] = v;
        }
    }
}

extern "C" void kernel_launch(void* const* d_in, const int* in_sizes, int n_in,
                              void* d_out, int out_size, void* d_ws, size_t ws_size,
                              hipStream_t stream) {
    const float* x  = (const float*)d_in[0];
    const float* Wp = (const float*)d_in[1];
    const float* bp = (const float*)d_in[2];
    const float* Wq = (const float*)d_in[3];
    float* out = (float*)d_out;
    unsigned short* Whi = (unsigned short*)d_ws;              // 512*1280*2B = 1.31 MB
    unsigned short* Wlo = Whi + WPLANE;                        // +1.31 MB

    pack_w_kernel<<<(WPLANE) / 256, 256, 0, stream>>>(Wp, Wq, Whi, Wlo);
    kanv_gemm<<<(MTOT / 128) * 4, 256, 0, stream>>>(x, Whi, Wlo, bp, out);
}